// Round 2
// baseline (114.105 us; speedup 1.0000x reference)
//
#include <hip/hip_runtime.h>

// Hamiltonian flow, separable H = sum(0.5 p^2 + 0.5 q^2 + 0.25 q^4):
//   dq/dt = p ;  dp/dt = -(q + q^3)
// Each (q,p) pair is independent. R1 (1 pair/thread) was latency-bound on the
// dependent FMA chain (VALUBusy 75%, 72us vs 19us issue floor). R2: 2 pairs
// per thread -> 4 independent FMA chains per wave, float4 ld/st, half the
// loop/addr overhead. 262144 pairs -> 131072 threads -> 512 blocks of 256.

__device__ __forceinline__ void rk4_step(float& q, float& p,
                                         float dt, float hdt, float dt6) {
    float u1 = q * q;
    float m1 = fmaf(u1, q, q);          // q + q^3
    float qa = fmaf(hdt, p, q);
    float pa = fmaf(-hdt, m1, p);

    float u2 = qa * qa;
    float m2 = fmaf(u2, qa, qa);
    float qb = fmaf(hdt, pa, q);
    float pb = fmaf(-hdt, m2, p);

    float u3 = qb * qb;
    float m3 = fmaf(u3, qb, qb);
    float qc = fmaf(dt, pb, q);
    float pc = fmaf(-dt, m3, p);

    float u4 = qc * qc;
    float m4 = fmaf(u4, qc, qc);

    float sq = fmaf(2.0f, pa, p);       // p + 2pa + 2pb + pc
    sq = fmaf(2.0f, pb, sq);
    sq += pc;
    q = fmaf(dt6, sq, q);

    float sp = fmaf(2.0f, m2, m1);      // m1 + 2m2 + 2m3 + m4
    sp = fmaf(2.0f, m3, sp);
    sp += m4;
    p = fmaf(-dt6, sp, p);
}

__global__ __launch_bounds__(256) void HamiltonianFlow_23957327577411_kernel(
    const float4* __restrict__ x0, float4* __restrict__ out, int n2)
{
    int i = blockIdx.x * blockDim.x + threadIdx.x;
    if (i >= n2) return;

    float4 v = x0[i];
    float q0 = v.x, p0 = v.y;           // pair 0
    float q1 = v.z, p1 = v.w;           // pair 1

    const float dt  = (float)(10.0 / 255.0);
    const float hdt = 0.5f * dt;
    const float dt6 = dt * (1.0f / 6.0f);

    #pragma unroll 5
    for (int s = 0; s < 255; ++s) {
        // Two independent pairs: compiler interleaves/packs the twin chains.
        rk4_step(q0, p0, dt, hdt, dt6);
        rk4_step(q1, p1, dt, hdt, dt6);
    }

    out[i] = make_float4(q0, p0, q1, p1);
}

extern "C" void kernel_launch(void* const* d_in, const int* in_sizes, int n_in,
                              void* d_out, int out_size, void* d_ws, size_t ws_size,
                              hipStream_t stream) {
    const float4* x0 = (const float4*)d_in[0];
    float4* out = (float4*)d_out;
    int n2 = in_sizes[0] / 4;           // thread count: 2 pairs (4 floats) each
    int block = 256;
    int grid = (n2 + block - 1) / block;
    HamiltonianFlow_23957327577411_kernel<<<grid, block, 0, stream>>>(x0, out, n2);
}

// Round 3
// 74.953 us; speedup vs baseline: 1.5224x; 1.5224x over previous
//
#include <hip/hip_runtime.h>

// Hamiltonian flow, separable H: dq/dt = p ; dp/dt = -(q + q^3).
// R1 (1 pair/thread): 72us, VALUBusy 75%. R2 (2 pairs/thread, scalar): 77us,
// no change -> NOT latency-bound; VALU issue-throughput-bound. R3: pack the
// two independent pairs into <2 x float> so the backend emits v_pk_fma_f32 /
// v_pk_mul_f32 (gfx90a+ packed fp32) -> dynamic VALU instruction count halves.
// 262144 pairs -> 131072 threads (2 pairs each) -> 512 blocks of 256.

typedef float v2f __attribute__((ext_vector_type(2)));

__device__ __forceinline__ v2f vfma(v2f a, v2f b, v2f c) {
    return __builtin_elementwise_fma(a, b, c);
}

__global__ __launch_bounds__(256) void HamiltonianFlow_23957327577411_kernel(
    const float4* __restrict__ x0, float4* __restrict__ out, int n2)
{
    int i = blockIdx.x * blockDim.x + threadIdx.x;
    if (i >= n2) return;

    float4 v = x0[i];
    // lane-packed: component 0 = pair 0, component 1 = pair 1
    v2f q = {v.x, v.z};
    v2f p = {v.y, v.w};

    const float dt_s  = (float)(10.0 / 255.0);
    const float hdt_s = 0.5f * dt_s;
    const float dt6_s = dt_s * (1.0f / 6.0f);

    const v2f dt   = {dt_s, dt_s};
    const v2f hdt  = {hdt_s, hdt_s};
    const v2f nhdt = {-hdt_s, -hdt_s};
    const v2f ndt  = {-dt_s, -dt_s};
    const v2f dt6  = {dt6_s, dt6_s};
    const v2f ndt6 = {-dt6_s, -dt6_s};
    const v2f two  = {2.0f, 2.0f};

    #pragma unroll 5
    for (int s = 0; s < 255; ++s) {
        // m_i = q_i + q_i^3 ; k_i(q) = p_i, k_i(p) = -m_i
        v2f u1 = q * q;
        v2f m1 = vfma(u1, q, q);
        v2f qa = vfma(hdt, p, q);
        v2f pa = vfma(nhdt, m1, p);

        v2f u2 = qa * qa;
        v2f m2 = vfma(u2, qa, qa);
        v2f qb = vfma(hdt, pa, q);
        v2f pb = vfma(nhdt, m2, p);

        v2f u3 = qb * qb;
        v2f m3 = vfma(u3, qb, qb);
        v2f qc = vfma(dt, pb, q);
        v2f pc = vfma(ndt, m3, p);

        v2f u4 = qc * qc;
        v2f m4 = vfma(u4, qc, qc);

        // q += dt/6 * (p + 2 pa + 2 pb + pc)
        v2f sq = vfma(two, pa, p);
        sq = vfma(two, pb, sq);
        sq = sq + pc;
        q = vfma(dt6, sq, q);

        // p -= dt/6 * (m1 + 2 m2 + 2 m3 + m4)
        v2f sp = vfma(two, m2, m1);
        sp = vfma(two, m3, sp);
        sp = sp + m4;
        p = vfma(ndt6, sp, p);
    }

    out[i] = make_float4(q.x, p.x, q.y, p.y);
}

extern "C" void kernel_launch(void* const* d_in, const int* in_sizes, int n_in,
                              void* d_out, int out_size, void* d_ws, size_t ws_size,
                              hipStream_t stream) {
    const float4* x0 = (const float4*)d_in[0];
    float4* out = (float4*)d_out;
    int n2 = in_sizes[0] / 4;           // 2 pairs (4 floats) per thread
    int block = 256;
    int grid = (n2 + block - 1) / block;
    HamiltonianFlow_23957327577411_kernel<<<grid, block, 0, stream>>>(x0, out, n2);
}

// Round 5
// 72.913 us; speedup vs baseline: 1.5649x; 1.0280x over previous
//
#include <hip/hip_runtime.h>

// Hamiltonian flow, separable H: dq/dt = p ; dp/dt = -(q + q^3), m(q)=q+q^3.
// R1 72us scalar -> R3 ~36us packed fp32 (v_pk_fma_f32): time scales with
// dynamic VALU instruction count. R4: algebraic RK4 reduction 22 -> 19 packed
// ops/step, same discretization:
//   qa = q + h p            (h = dt/2)
//   qb = qa - (dt^2/4) m1           [pa eliminated]
//   q2 = q + dt p
//   qc = q2 - (dt^2/2) m2           [pb eliminated]
//   q' = q2 - (dt^2/6)(m1+m2+m3)    [pc + k-sum eliminated]
//   p' = p  - (dt/6)(m1+2m2+2m3+m4)
// R4 bench died with a host-side core dump (no absmax, no rocprof) -- infra
// crash, not a kernel defect. R5 = identical resubmission.
// 262144 pairs -> 131072 threads (2 pairs packed per thread) -> 512x256.

typedef float v2f __attribute__((ext_vector_type(2)));

__device__ __forceinline__ v2f vfma(v2f a, v2f b, v2f c) {
    return __builtin_elementwise_fma(a, b, c);
}

__global__ __launch_bounds__(256) void HamiltonianFlow_23957327577411_kernel(
    const float4* __restrict__ x0, float4* __restrict__ out, int n2)
{
    int i = blockIdx.x * blockDim.x + threadIdx.x;
    if (i >= n2) return;

    float4 v = x0[i];
    v2f q = {v.x, v.z};   // component 0 = pair 0, component 1 = pair 1
    v2f p = {v.y, v.w};

    const float dt_s = (float)(10.0 / 255.0);
    const float h_s  = 0.5f * dt_s;

    const v2f dt   = {dt_s, dt_s};
    const v2f h    = {h_s, h_s};
    const v2f nc1  = {-dt_s * dt_s * 0.25f,        -dt_s * dt_s * 0.25f};        // -dt^2/4
    const v2f nc2  = {-dt_s * dt_s * 0.5f,         -dt_s * dt_s * 0.5f};         // -dt^2/2
    const v2f nc3  = {-dt_s * dt_s * (1.0f/6.0f),  -dt_s * dt_s * (1.0f/6.0f)};  // -dt^2/6
    const v2f ndt6 = {-dt_s * (1.0f/6.0f),         -dt_s * (1.0f/6.0f)};         // -dt/6
    const v2f two  = {2.0f, 2.0f};

    #pragma unroll 5
    for (int s = 0; s < 255; ++s) {
        v2f u1 = q * q;
        v2f m1 = vfma(u1, q, q);        // m(q)
        v2f qa = vfma(h,  p, q);        // q + h p
        v2f q2 = vfma(dt, p, q);        // q + dt p

        v2f u2 = qa * qa;
        v2f m2 = vfma(u2, qa, qa);      // m(qa)
        v2f qb = vfma(nc1, m1, qa);     // qa - (dt^2/4) m1

        v2f u3 = qb * qb;
        v2f m3 = vfma(u3, qb, qb);      // m(qb)
        v2f qc = vfma(nc2, m2, q2);     // q2 - (dt^2/2) m2

        v2f u4 = qc * qc;
        v2f m4 = vfma(u4, qc, qc);      // m(qc)

        // p' = p - dt/6 (m1 + 2m2 + 2m3 + m4)
        v2f s1 = vfma(two, m2, m1);
        v2f s2 = vfma(two, m3, s1);
        v2f s3 = s2 + m4;
        p = vfma(ndt6, s3, p);

        // q' = q2 - dt^2/6 (m1 + m2 + m3)
        v2f t1 = m1 + m2;
        v2f t2 = t1 + m3;
        q = vfma(nc3, t2, q2);
    }

    out[i] = make_float4(q.x, p.x, q.y, p.y);
}

extern "C" void kernel_launch(void* const* d_in, const int* in_sizes, int n_in,
                              void* d_out, int out_size, void* d_ws, size_t ws_size,
                              hipStream_t stream) {
    const float4* x0 = (const float4*)d_in[0];
    float4* out = (float4*)d_out;
    int n2 = in_sizes[0] / 4;           // 2 pairs (4 floats) per thread
    int block = 256;
    int grid = (n2 + block - 1) / block;
    HamiltonianFlow_23957327577411_kernel<<<grid, block, 0, stream>>>(x0, out, n2);
}